// Round 3
// baseline (153.233 us; speedup 1.0000x reference)
//
#include <hip/hip_runtime.h>

// MaskedTimeAttention: B=32, En=512, De=64, D_en=D_de=U=128 (fixed by setup_inputs)
// ws layout: att_en (32*512*128 f32 = 8 MB) | att_de_scaled (32*64*128 f32 = 1 MB)

#define TWO_LOG2E 2.8853900817779268f
#define LOG2E     1.4426950408889634f

__device__ __forceinline__ float fexp2(float x){
#if __has_builtin(__builtin_amdgcn_exp2f)
  return __builtin_amdgcn_exp2f(x);
#else
  float r; asm("v_exp_f32 %0, %1" : "=v"(r) : "v"(x)); return r;
#endif
}
__device__ __forceinline__ float frcp(float x){
#if __has_builtin(__builtin_amdgcn_rcpf)
  return __builtin_amdgcn_rcpf(x);
#else
  float r; asm("v_rcp_f32 %0, %1" : "=v"(r) : "v"(x)); return r;
#endif
}

// ---------------- Kernel A: att_en = (en*mask)@w_en ; att_de_sc = (de@w_de)*2log2e ----
// grid: 512 en-blocks (32 rows each) + 64 de-blocks. 256 threads. LDS 80KB -> 2 blocks/CU.
__global__ __launch_bounds__(256) void k_gemms(
    const float* __restrict__ en_seq, const float* __restrict__ de_seq,
    const float* __restrict__ w_en, const float* __restrict__ w_de,
    const int* __restrict__ mask,
    float* __restrict__ att_en, float* __restrict__ att_de_sc)
{
  __shared__ __align__(16) float Ws[128*128];  // 64 KB
  __shared__ __align__(16) float As[32*128];   // 16 KB
  const int bi = blockIdx.x, tid = threadIdx.x;
  const float* A; const float* W; float* O; int row0; bool masked;
  if (bi < 512) { A = en_seq; W = w_en; O = att_en;    row0 = bi*32;        masked = true;  }
  else          { A = de_seq; W = w_de; O = att_de_sc; row0 = (bi-512)*32;  masked = false; }

  const float4* W4 = (const float4*)W;
  float4* Ws4 = (float4*)Ws;
#pragma unroll
  for (int i = 0; i < 16; ++i) Ws4[tid + 256*i] = W4[tid + 256*i];
  const float4* A4 = (const float4*)(A + row0*128);
  float4* As4 = (float4*)As;
#pragma unroll
  for (int i = 0; i < 4; ++i) As4[tid + 256*i] = A4[tid + 256*i];
  __syncthreads();

  const int c0 = (tid & 31) * 4;   // output col (float idx)
  const int r0 = (tid >> 5) * 4;   // output row within tile
  float acc[4][4] = {};
  for (int k = 0; k < 128; k += 4) {
    float4 av[4], wv[4];
#pragma unroll
    for (int r = 0; r < 4; ++r) av[r] = *(const float4*)&As[(r0+r)*128 + k];   // broadcast
#pragma unroll
    for (int kk = 0; kk < 4; ++kk) wv[kk] = *(const float4*)&Ws[(k+kk)*128 + c0];
#pragma unroll
    for (int r = 0; r < 4; ++r) {
      const float* ar = (const float*)&av[r];
#pragma unroll
      for (int kk = 0; kk < 4; ++kk) {
        acc[r][0] = fmaf(ar[kk], wv[kk].x, acc[r][0]);
        acc[r][1] = fmaf(ar[kk], wv[kk].y, acc[r][1]);
        acc[r][2] = fmaf(ar[kk], wv[kk].z, acc[r][2]);
        acc[r][3] = fmaf(ar[kk], wv[kk].w, acc[r][3]);
      }
    }
  }
#pragma unroll
  for (int r = 0; r < 4; ++r) {
    const int row = row0 + r0 + r;
    // row-scale commutes with right-multiplication: (en*m)@W == m*(en@W)
    const float m = masked ? (float)mask[row] : TWO_LOG2E;
    float4 o = { acc[r][0]*m, acc[r][1]*m, acc[r][2]*m, acc[r][3]*m };
    *(float4*)&O[row*128 + c0] = o;
  }
}

// ---------------- Kernel B: fused tanh-score + softmax + weighted sum ----------------
// grid: 256 blocks = (b, d-group of 8). 512 threads = 8 waves, wave w owns d = dg*8+w,
// lane l owns e = t*64+l across 8 e-tiles. LDS ~90.6 KB -> 1 block/CU.
#define PAD 132          // tile row stride (floats); uniform bank spread for b128 reads
#define TILE_F4 2048     // 64 rows * 32 float4

__global__ __launch_bounds__(512) void k_att(
    const float* __restrict__ att_en, const float* __restrict__ att_de_sc,
    const float* __restrict__ nu, const int* __restrict__ mask,
    const float* __restrict__ en_seq, const float* __restrict__ de_seq,
    float* __restrict__ out)
{
  __shared__ __align__(16) float smem[22656];       // 90624 B
  float* const buf0  = smem;                        // 8448 floats (64 x 132)
  float* const buf1  = smem + 8448;
  float* const adC_s = smem + 16896;                // 8 x 128 (pre-scaled att_de)
  float* const nu2_s = smem + 17920;                // 128   (-2*nu)
  float* const m_s   = smem + 18048;                // 512   (mask as float)
  float* const alph  = smem + 18560;                // 8 x 512 (mu, then alphas)
  float* const part  = smem;                        // aliases buf0 (pass-2 partials)

  const int tid = threadIdx.x;
  const int l = tid & 63, w = tid >> 6;
  const int b = blockIdx.x >> 3, dg = blockIdx.x & 7;
  const int d = dg*8 + w;

  // ---- initial staging (one barrier) ----
  if (tid < 256)
    ((float4*)adC_s)[tid] = ((const float4*)(att_de_sc + (b*64 + dg*8)*128))[tid];
  if (tid >= 256 && tid < 384)
    nu2_s[tid-256] = -2.0f * nu[tid-256];
  m_s[tid] = (float)mask[b*512 + tid];

  float4 rg[4];
  const float4* AE4 = (const float4*)(att_en + (size_t)b * (512*128));
#define SLOAD(t) { _Pragma("unroll") for (int i_=0;i_<4;++i_) rg[i_] = AE4[(t)*TILE_F4 + tid + 512*i_]; }
#define SWRITE(bp) { _Pragma("unroll") for (int i_=0;i_<4;++i_){ const int f4i_ = tid + 512*i_; \
                     *(float4*)&(bp)[(f4i_>>5)*PAD + (f4i_&31)*4] = rg[i_]; } }
  SLOAD(0);
  SWRITE(buf0);
  __syncthreads();

  float snu2 = 0.f;
#pragma unroll
  for (int i = 0; i < 32; ++i) { float4 v = ((const float4*)nu2_s)[i]; snu2 += (v.x+v.y)+(v.z+v.w); }
  const float S_nu = -0.5f * snu2;   // sum(nu);  tanh-sum = S_nu + sum(rcp * (-2 nu))

  // ---- pass 1: mu[d][e], double-buffered e-tiles, issue-early/write-late staging ----
  for (int t = 0; t < 8; ++t) {
    if (t < 7) SLOAD(t+1);                           // loads in flight across compute
    const float4* row4 = (const float4*)(((t & 1) ? buf1 : buf0) + l*PAD);
    const float4* ad4  = (const float4*)(adC_s + w*128);
    const float4* nv4  = (const float4*)nu2_s;
    float a0=0.f, a1=0.f, a2=0.f, a3=0.f;
#pragma unroll 4
    for (int uc = 0; uc < 32; ++uc) {
      float4 ae = row4[uc], ad = ad4[uc], nv = nv4[uc];
      float e0 = fexp2(fmaf(ae.x, TWO_LOG2E, ad.x));   // e^{2(att_en+att_de)}
      float e1 = fexp2(fmaf(ae.y, TWO_LOG2E, ad.y));
      float e2 = fexp2(fmaf(ae.z, TWO_LOG2E, ad.z));
      float e3 = fexp2(fmaf(ae.w, TWO_LOG2E, ad.w));
      a0 = fmaf(frcp(e0 + 1.f), nv.x, a0);             // tanh = 1 - 2/(t+1)
      a1 = fmaf(frcp(e1 + 1.f), nv.y, a1);
      a2 = fmaf(frcp(e2 + 1.f), nv.z, a2);
      a3 = fmaf(frcp(e3 + 1.f), nv.w, a3);
    }
    alph[w*512 + t*64 + l] = S_nu + ((a0+a1)+(a2+a3)); // mu (own-wave row: no barrier needed)
    if (t < 7) {
      __syncthreads();                                  // everyone done reading other buffer
      SWRITE(((t & 1) ? buf0 : buf1));
      __syncthreads();                                  // writes visible before next reads
    }
  }

  // ---- wave softmax over En (row d lives in one wave: 8 regs x 64 lanes) ----
  // scrambled-layout bias: bias[b,d,e] = (mask[b, d*8 + e/64] - 1)*1e4, e/64 == t
  float v[8]; float mx = -3.0e38f;
#pragma unroll
  for (int t = 0; t < 8; ++t) {
    v[t] = alph[w*512 + t*64 + l] + (m_s[d*8 + t] - 1.f) * 10000.f;
    mx = fmaxf(mx, v[t]);
  }
#pragma unroll
  for (int off = 32; off > 0; off >>= 1) mx = fmaxf(mx, __shfl_xor(mx, off, 64));
  float s = 0.f, p[8];
#pragma unroll
  for (int t = 0; t < 8; ++t) { p[t] = fexp2((v[t]-mx)*LOG2E); s += p[t]; }
#pragma unroll
  for (int off = 32; off > 0; off >>= 1) s += __shfl_xor(s, off, 64);
  const float inv = frcp(s);
#pragma unroll
  for (int t = 0; t < 8; ++t)                      // fold en-mask into alpha:
    alph[w*512 + t*64 + l] = p[t]*inv*m_s[t*64 + l];   // sum_e a*(m*en) = sum_e (a*m)*en
  __syncthreads();

  // ---- pass 2: sum_en = alphas @ en_seq. wave w owns e-range [w*64, w*64+64),
  //      accumulates partials for ALL 8 d's; en rows read coalesced from global. ----
  float acc2[8][2] = {};
  const float* enB = en_seq + (size_t)b * (512*128);
#pragma unroll 4
  for (int ei = 0; ei < 64; ++ei) {
    const int e = w*64 + ei;
    const float2 ev = *(const float2*)&enB[e*128 + l*2];
#pragma unroll
    for (int dd = 0; dd < 8; ++dd) {
      const float a = alph[dd*512 + e];            // LDS broadcast
      acc2[dd][0] = fmaf(a, ev.x, acc2[dd][0]);
      acc2[dd][1] = fmaf(a, ev.y, acc2[dd][1]);
    }
  }
#pragma unroll
  for (int dd = 0; dd < 8; ++dd) {
    float2 t2 = { acc2[dd][0], acc2[dd][1] };
    *(float2*)&part[(w*8 + dd)*128 + l*2] = t2;    // part aliases buf0 (pass 1 done)
  }
  __syncthreads();

  // ---- cross-wave reduce + output (de_seq copy fused) ----
  const int brow = b*64 + dg*8;
#pragma unroll
  for (int ii = 0; ii < 2; ++ii) {
    const int idx = tid + ii*512;
    const int dd = idx >> 7, f = idx & 127;
    float s2 = 0.f;
#pragma unroll
    for (int ww = 0; ww < 8; ++ww) s2 += part[(ww*8 + dd)*128 + f];
    const int drow = brow + dd;
    out[drow*256 + f]       = de_seq[drow*128 + f];
    out[drow*256 + 128 + f] = s2;
  }
}

extern "C" void kernel_launch(void* const* d_in, const int* in_sizes, int n_in,
                              void* d_out, int out_size, void* d_ws, size_t ws_size,
                              hipStream_t stream) {
  const float* en_seq = (const float*)d_in[0];   // (32,512,128)
  const float* de_seq = (const float*)d_in[1];   // (32,64,128)
  const int*   mask   = (const int*)  d_in[2];   // (32,512)
  const float* w_en   = (const float*)d_in[3];   // (128,128)
  const float* w_de   = (const float*)d_in[4];   // (128,128)
  const float* nu     = (const float*)d_in[5];   // (128,1)
  float* out = (float*)d_out;                    // (32,64,256)

  float* att_en    = (float*)d_ws;               // 32*512*128 f32
  float* att_de_sc = att_en + 32*512*128;        // 32*64*128  f32  (needs ~9.4 MB ws)

  k_gemms<<<576, 256, 0, stream>>>(en_seq, de_seq, w_en, w_de, mask, att_en, att_de_sc);
  k_att<<<256, 512, 0, stream>>>(att_en, att_de_sc, nu, mask, en_seq, de_seq, out);
}

// Round 5
// 132.374 us; speedup vs baseline: 1.1576x; 1.1576x over previous
//
#include <hip/hip_runtime.h>

// MaskedTimeAttention: B=32, En=512, De=64, D_en=D_de=U=128
// ws: att_en (32*512*128 f32 = 8 MB) | att_de_sc (32*64*128 f32 = 1 MB)
// XCD plan: all blocks touching batch b run on XCD b%8 (bid%8 == b%8), so
// att_en[b]/en_seq[b] stay in one XCD's L2 from producer to consumer.

#define TWO_LOG2E 2.8853900817779268f
#define LOG2E     1.4426950408889634f

__device__ __forceinline__ float fexp2(float x){
#if __has_builtin(__builtin_amdgcn_exp2f)
  return __builtin_amdgcn_exp2f(x);
#else
  float r; asm("v_exp_f32 %0, %1" : "=v"(r) : "v"(x)); return r;
#endif
}
__device__ __forceinline__ float frcp(float x){
#if __has_builtin(__builtin_amdgcn_rcpf)
  return __builtin_amdgcn_rcpf(x);
#else
  float r; asm("v_rcp_f32 %0, %1" : "=v"(r) : "v"(x)); return r;
#endif
}

// ---------------- Kernel A: att_en = (en*mask)@w_en ; att_de_sc = (de@w_de)*2log2e ----
// 576 blocks x 256 thr. LDS 48KB (half-K W, two phases) -> 3 blocks/CU.
// en blocks: bi<512: b=bi&31, j=bi>>5, rows (b*512 + j*32) -> bid%8 == b%8.
// de blocks: q=bi-512: b=q&31, jj=q>>5, rows (b*64 + jj*32) -> bid%8 == b%8.
__global__ __launch_bounds__(256) void k_gemms(
    const float* __restrict__ en_seq, const float* __restrict__ de_seq,
    const float* __restrict__ w_en, const float* __restrict__ w_de,
    const int* __restrict__ mask,
    float* __restrict__ att_en, float* __restrict__ att_de_sc)
{
  __shared__ __align__(16) float Ws[64*128];   // 32 KB (half of K)
  __shared__ __align__(16) float As[32*128];   // 16 KB
  const int bi = blockIdx.x, tid = threadIdx.x;
  const float* A; const float* W; float* O; int row0; bool masked;
  if (bi < 512) { int b = bi & 31, j = bi >> 5;
                  A = en_seq; W = w_en; O = att_en;    row0 = b*512 + j*32; masked = true; }
  else          { int q = bi - 512; int b = q & 31, jj = q >> 5;
                  A = de_seq; W = w_de; O = att_de_sc; row0 = b*64 + jj*32; masked = false; }

  const float4* A4 = (const float4*)(A + row0*128);
  float4* As4 = (float4*)As;
#pragma unroll
  for (int i = 0; i < 4; ++i) As4[tid + 256*i] = A4[tid + 256*i];

  const int c0 = (tid & 31) * 4;   // output col
  const int r0 = (tid >> 5) * 4;   // output row within tile
  float acc[4][4] = {};

  for (int ph = 0; ph < 2; ++ph) {
    if (ph) __syncthreads();                       // phase-0 compute done before overwrite
    const float4* W4 = (const float4*)(W + ph*64*128);
    float4* Ws4 = (float4*)Ws;
#pragma unroll
    for (int i = 0; i < 8; ++i) Ws4[tid + 256*i] = W4[tid + 256*i];
    __syncthreads();
    for (int k = 0; k < 64; k += 4) {
      const int kg = ph*64 + k;
      float4 av[4], wv[4];
#pragma unroll
      for (int r = 0; r < 4; ++r) av[r] = *(const float4*)&As[(r0+r)*128 + kg];  // broadcast
#pragma unroll
      for (int kk = 0; kk < 4; ++kk) wv[kk] = *(const float4*)&Ws[(k+kk)*128 + c0];
#pragma unroll
      for (int r = 0; r < 4; ++r) {
        const float* ar = (const float*)&av[r];
#pragma unroll
        for (int kk = 0; kk < 4; ++kk) {
          acc[r][0] = fmaf(ar[kk], wv[kk].x, acc[r][0]);
          acc[r][1] = fmaf(ar[kk], wv[kk].y, acc[r][1]);
          acc[r][2] = fmaf(ar[kk], wv[kk].z, acc[r][2]);
          acc[r][3] = fmaf(ar[kk], wv[kk].w, acc[r][3]);
        }
      }
    }
  }
#pragma unroll
  for (int r = 0; r < 4; ++r) {
    const int row = row0 + r0 + r;
    // (en*m)@W == m*(en@W); de-path folds the 2*log2e exp2 prescale instead.
    const float m = masked ? (float)mask[row] : TWO_LOG2E;
    float4 o = { acc[r][0]*m, acc[r][1]*m, acc[r][2]*m, acc[r][3]*m };
    *(float4*)&O[row*128 + c0] = o;
  }
}

// ---------------- Kernel B: fused tanh-score + softmax + weighted sum ----------------
// 256 blocks (b = bid&31, dg = bid>>5 -> XCD = b%8), 512 thr = 8 waves.
// Pass 1 mapping: lane l -> (dP = l&7, er = l>>3); wave w covers e = t*64 + w*8 + er.
//   8 lanes share each tile word (multicast) -> LDS bytes/inst /8.
// Tile: linear [64][128] f32 with XOR swizzle quad^=(row&7) -> conflict-free b128.
// LDS 55.4 KB -> 2 blocks/CU.
__global__ __launch_bounds__(512) void k_att(
    const float* __restrict__ att_en, const float* __restrict__ att_de_sc,
    const float* __restrict__ nu, const int* __restrict__ mask,
    const float* __restrict__ en_seq, const float* __restrict__ de_seq,
    float* __restrict__ out)
{
  __shared__ __align__(16) float smem[13864];
  float* const tile = smem;            // 8192 f32 (64 x 128, swizzled); later: part
  float* const alph = smem + 8192;     // 8 x 513 (padded rows: stride 513 kills 8-way)
  float* const m_s  = smem + 12296;    // 512
  float* const adC  = smem + 12808;    // 8 x 132 (padded: 8-lane multicast conflict-free)
  float* const part = smem;            // alias of tile (pass-2 partials)

  const int tid = threadIdx.x;
  const int l = tid & 63, w = tid >> 6;
  const int b = blockIdx.x & 31, dg = blockIdx.x >> 5;

  // ---- staging: att_de rows (padded), mask ----
  if (tid < 256) {
    const int row = tid >> 5, q = tid & 31;
    *(float4*)&adC[row*132 + q*4] =
        *(const float4*)&att_de_sc[(b*64 + dg*8 + row)*128 + q*4];
  }
  m_s[tid] = (float)mask[b*512 + tid];

  // S_nu = sum(nu): lane-parallel + shfl reduce (tanh*nu sum = S_nu - 2*sum(rcp*nu))
  float snu = nu[l] + nu[l + 64];
#pragma unroll
  for (int off = 32; off > 0; off >>= 1) snu += __shfl_xor(snu, off, 64);
  const float S_nu = snu;

  float4 rg[4];
  const float4* AE4 = (const float4*)(att_en + (size_t)b * (512*128));
#define SLOAD(t) { _Pragma("unroll") for (int i_=0;i_<4;++i_) rg[i_] = AE4[(t)*2048 + tid + 512*i_]; }
#define SWRITE() { _Pragma("unroll") for (int i_=0;i_<4;++i_){ const int f4i_ = tid + 512*i_; \
                   const int row_ = f4i_>>5, q_ = f4i_&31; \
                   *(float4*)&tile[row_*128 + ((q_ ^ (row_&7))<<2)] = rg[i_]; } }
  SLOAD(0);
  SWRITE();
  __syncthreads();

  // ---- pass 1: mu partial (sum over u of rcp(e^{2x}+1)*nu) ----
  const int dP = l & 7, er = l >> 3;
  const int r  = w*8 + er;                 // tile row (e within tile)
  const float* adrow = adC + dP*132;       // att_de_sc row for this lane's d
  for (int t = 0; t < 8; ++t) {
    if (t < 7) SLOAD(t+1);                 // loads in flight across compute (T14)
    float a0=0.f, a1=0.f, a2=0.f, a3=0.f;
#pragma unroll 4
    for (int uc = 0; uc < 32; ++uc) {
      float4 ae = *(const float4*)&tile[r*128 + ((uc ^ (r&7))<<2)];   // 8-lane multicast
      float4 ad = *(const float4*)&adrow[uc<<2];                       // padded multicast
      float4 nv = *(const float4*)&nu[uc<<2];                          // uniform -> s_load
      float e0 = fexp2(fmaf(ae.x, TWO_LOG2E, ad.x));
      float e1 = fexp2(fmaf(ae.y, TWO_LOG2E, ad.y));
      float e2 = fexp2(fmaf(ae.z, TWO_LOG2E, ad.z));
      float e3 = fexp2(fmaf(ae.w, TWO_LOG2E, ad.w));
      a0 = fmaf(frcp(e0 + 1.f), nv.x, a0);
      a1 = fmaf(frcp(e1 + 1.f), nv.y, a1);
      a2 = fmaf(frcp(e2 + 1.f), nv.z, a2);
      a3 = fmaf(frcp(e3 + 1.f), nv.w, a3);
    }
    alph[dP*513 + t*64 + w*8 + er] = (a0+a1)+(a2+a3);
    __syncthreads();                       // all reads of tile done
    if (t < 7) { SWRITE(); __syncthreads(); }
  }

  // ---- wave softmax: wave w owns d = dg*8+w; scrambled bias mask[b, d*8 + e/64]
  //      -> m_s[(dg*8+w)*8 + t] = m_s[dg*64 + w*8 + t]  (AUDIT FIX: dg term) ----
  float v[8]; float mx = -3.0e38f;
#pragma unroll
  for (int t = 0; t < 8; ++t) {
    v[t] = S_nu - 2.f*alph[w*513 + t*64 + l] + (m_s[dg*64 + w*8 + t] - 1.f) * 10000.f;
    mx = fmaxf(mx, v[t]);
  }
#pragma unroll
  for (int off = 32; off > 0; off >>= 1) mx = fmaxf(mx, __shfl_xor(mx, off, 64));
  float s = 0.f, p[8];
#pragma unroll
  for (int t = 0; t < 8; ++t) { p[t] = fexp2((v[t]-mx)*LOG2E); s += p[t]; }
#pragma unroll
  for (int off = 32; off > 0; off >>= 1) s += __shfl_xor(s, off, 64);
  const float inv = frcp(s);
#pragma unroll
  for (int t = 0; t < 8; ++t)              // fold en-mask: sum_e a*(m*en) = (a*m)*en
    alph[w*513 + t*64 + l] = p[t]*inv*m_s[t*64 + l];
  __syncthreads();

  // ---- pass 2: sum_en = alphas @ en_seq; lane: f0=(l&15)*8, e-sub=l>>4 ----
  const int f0 = (l & 15) * 8, es = l >> 4;
  float acc2[8][8] = {};
  const float* enB = en_seq + (size_t)b * (512*128);
  for (int it = 0; it < 16; ++it) {
    const int e = w*64 + it*4 + es;
    float4 ev0 = *(const float4*)&enB[e*128 + f0];
    float4 ev1 = *(const float4*)&enB[e*128 + f0 + 4];
#pragma unroll
    for (int dd = 0; dd < 8; ++dd) {
      const float a = alph[dd*513 + e];    // broadcast to 16 lanes
      acc2[dd][0] = fmaf(a, ev0.x, acc2[dd][0]);
      acc2[dd][1] = fmaf(a, ev0.y, acc2[dd][1]);
      acc2[dd][2] = fmaf(a, ev0.z, acc2[dd][2]);
      acc2[dd][3] = fmaf(a, ev0.w, acc2[dd][3]);
      acc2[dd][4] = fmaf(a, ev1.x, acc2[dd][4]);
      acc2[dd][5] = fmaf(a, ev1.y, acc2[dd][5]);
      acc2[dd][6] = fmaf(a, ev1.z, acc2[dd][6]);
      acc2[dd][7] = fmaf(a, ev1.w, acc2[dd][7]);
    }
  }
  // reduce across the 4 e-sub lane groups (l^16, l^32)
#pragma unroll
  for (int dd = 0; dd < 8; ++dd)
#pragma unroll
    for (int j = 0; j < 8; ++j) {
      acc2[dd][j] += __shfl_xor(acc2[dd][j], 16, 64);
      acc2[dd][j] += __shfl_xor(acc2[dd][j], 32, 64);
    }
  if (l < 16) {
#pragma unroll
    for (int dd = 0; dd < 8; ++dd) {
      float4 t0 = { acc2[dd][0], acc2[dd][1], acc2[dd][2], acc2[dd][3] };
      float4 t1 = { acc2[dd][4], acc2[dd][5], acc2[dd][6], acc2[dd][7] };
      *(float4*)&part[(w*8 + dd)*128 + f0]     = t0;   // part aliases tile (pass 1 done)
      *(float4*)&part[(w*8 + dd)*128 + f0 + 4] = t1;
    }
  }
  __syncthreads();

  // ---- cross-wave reduce + output (de_seq copy fused) ----
  if (tid < 256) {
    const int dd = tid >> 5, fq = (tid & 31) * 4;
    float4 s2 = {0.f, 0.f, 0.f, 0.f};
#pragma unroll
    for (int ww = 0; ww < 8; ++ww) {
      float4 pv = *(const float4*)&part[(ww*8 + dd)*128 + fq];
      s2.x += pv.x; s2.y += pv.y; s2.z += pv.z; s2.w += pv.w;
    }
    const int drow = b*64 + dg*8 + dd;
    *(float4*)&out[drow*256 + fq]       = *(const float4*)&de_seq[drow*128 + fq];
    *(float4*)&out[drow*256 + 128 + fq] = s2;
  }
}

extern "C" void kernel_launch(void* const* d_in, const int* in_sizes, int n_in,
                              void* d_out, int out_size, void* d_ws, size_t ws_size,
                              hipStream_t stream) {
  const float* en_seq = (const float*)d_in[0];   // (32,512,128)
  const float* de_seq = (const float*)d_in[1];   // (32,64,128)
  const int*   mask   = (const int*)  d_in[2];   // (32,512)
  const float* w_en   = (const float*)d_in[3];   // (128,128)
  const float* w_de   = (const float*)d_in[4];   // (128,128)
  const float* nu     = (const float*)d_in[5];   // (128,1)
  float* out = (float*)d_out;                    // (32,64,256)

  float* att_en    = (float*)d_ws;               // 32*512*128 f32
  float* att_de_sc = att_en + 32*512*128;        // 32*64*128  f32

  k_gemms<<<576, 256, 0, stream>>>(en_seq, de_seq, w_en, w_de, mask, att_en, att_de_sc);
  k_att<<<256, 512, 0, stream>>>(att_en, att_de_sc, nu, mask, en_seq, de_seq, out);
}